// Round 6
// baseline (158.112 us; speedup 1.0000x reference)
//
#include <hip/hip_runtime.h>
#include <math.h>

// Problem constants: B=32, C=64, H=128, W=128
#define HW 16384     // 128*128 plane elements
#define NPLANE 2048  // B*C planes

typedef __bf16 bf16x8 __attribute__((ext_vector_type(8)));
typedef float  f32x4  __attribute__((ext_vector_type(4)));

// ---------------------------------------------------------------------------
// 2D WHT(128x128) == 1D WHT(16384) over the flattened plane (H2^(x)14).
// 512 threads, 32 elems/thread (8 float4). Each block pipelines 4 planes:
// plane p+1's global loads issue after plane p's Phase-A LDS stores and stay
// in flight across raw s_barriers (no vmcnt drain), hiding HBM latency under
// the LDS-only phases. Bit split / LDS swizzle identical to R5 (verified).
// ---------------------------------------------------------------------------

__device__ __forceinline__ void wg_barrier() {
    __builtin_amdgcn_sched_barrier(0);
    asm volatile("s_waitcnt lgkmcnt(0)");
    __builtin_amdgcn_s_barrier();
    __builtin_amdgcn_sched_barrier(0);
}

__device__ __forceinline__ void bf_quad(float4& a) {
    float s0 = a.x + a.y, d0 = a.x - a.y;
    float s1 = a.z + a.w, d1 = a.z - a.w;
    a.x = s0 + s1; a.y = d0 + d1; a.z = s0 - s1; a.w = d0 - d1;
}

__device__ __forceinline__ void bf_pair(float4& a, float4& b) {
    float4 s, d;
    s.x = a.x + b.x; s.y = a.y + b.y; s.z = a.z + b.z; s.w = a.w + b.w;
    d.x = a.x - b.x; d.y = a.y - b.y; d.z = a.z - b.z; d.w = a.w - b.w;
    a = s; b = d;
}

__device__ __forceinline__ void bf_regs3(float4 (&r)[8]) {
    #pragma unroll
    for (int m = 1; m <= 4; m <<= 1) {
        #pragma unroll
        for (int j = 0; j < 8; ++j) {
            if (!(j & m)) bf_pair(r[j], r[j | m]);
        }
    }
}

// Phase A: bits {0,1} in-quad + {11,12,13} regs, then swizzled scatter-store.
__device__ __forceinline__ void phaseA(float* __restrict__ lds,
                                       float4 (&r)[8], int t) {
    #pragma unroll
    for (int j = 0; j < 8; ++j) bf_quad(r[j]);
    bf_regs3(r);
    const int physT = (t & 3)
                    + ((((t >> 5) ^ (t >> 4)) & 1) << 4)
                    + (((t >> 6) & 7) << 5)
                    + (((t >> 2) & 7) << 8);
    const int swc = (t >> 2) & 3;
    #pragma unroll
    for (int j = 0; j < 8; ++j) {
        float* b = lds + physT + j * 2048;
        b[(0 ^ swc) << 2] = r[j].x;
        b[(1 ^ swc) << 2] = r[j].y;
        b[(2 ^ swc) << 2] = r[j].z;
        b[(3 ^ swc) << 2] = r[j].w;
    }
}

// Phase B: bits {2,3} in-quad + {4,5,6} regs, LDS in-place b128.
__device__ __forceinline__ void phaseB(float* __restrict__ lds,
                                       float4 (&r)[8], int t) {
    const int baseT = ((t & 63) << 2) + ((t >> 6) << 11);
    int addr[8];
    #pragma unroll
    for (int j = 0; j < 8; ++j) {
        addr[j] = (baseT ^ ((j & 3) << 2) ^ ((j >> 2) << 4)) + (j << 8);
        r[j] = *reinterpret_cast<const float4*>(lds + addr[j]);
    }
    #pragma unroll
    for (int j = 0; j < 8; ++j) bf_quad(r[j]);
    bf_regs3(r);
    #pragma unroll
    for (int j = 0; j < 8; ++j)
        *reinterpret_cast<float4*>(lds + addr[j]) = r[j];
}

// Phase C: gather b32, bits {7,8} in-quad + {9,10} regs.
__device__ __forceinline__ void phaseC(const float* __restrict__ lds,
                                       float4 (&r)[8], int t) {
    const int t0 = t & 1, t1 = (t >> 1) & 1, t2 = (t >> 2) & 1;
    const int t3 = (t >> 3) & 1, t4 = (t >> 4) & 1, t5 = (t >> 5) & 1;
    const int cT = t1 + (t2 << 1) + ((t0 ^ t4) << 3)
                 + (t3 << 8) + (t4 << 9) + (t5 << 10) + ((t >> 6) << 11);
    #pragma unroll
    for (int j = 0; j < 8; ++j) {
        const int a = cT + ((((j >> 2) ^ t3)) << 2)
                    + ((j & 1) << 6) + (((j >> 1) & 1) << 7);
        float4 q;
        q.x = lds[a + ((0 ^ t5) << 4)];
        q.y = lds[a + ((1 ^ t5) << 4)];
        q.z = lds[a + ((0 ^ t5) << 4) + (1 << 5)];
        q.w = lds[a + ((1 ^ t5) << 4) + (1 << 5)];
        r[j] = q;
    }
    #pragma unroll
    for (int j = 0; j < 8; ++j) bf_quad(r[j]);
    #pragma unroll
    for (int m = 1; m <= 2; m <<= 1) {
        #pragma unroll
        for (int j = 0; j < 8; ++j) {
            if (!(j & m)) bf_pair(r[j], r[j | m]);
        }
    }
}

__global__ __launch_bounds__(512) void k_wht2d_fwd(const float* __restrict__ x,
                                                   float* __restrict__ out) {
    __shared__ float lds[HW];  // 64 KiB
    const int t = threadIdx.x;
    const size_t base = (size_t)blockIdx.x * 4 * HW;

    float4 r[8], nxt[8];
    {
        const float4* s4 = reinterpret_cast<const float4*>(x + base);
        #pragma unroll
        for (int j = 0; j < 8; ++j) r[j] = s4[t + j * 512];
    }

    #pragma unroll
    for (int p = 0; p < 4; ++p) {
        phaseA(lds, r, t);
        if (p < 3) {  // prefetch next plane; stays in flight across barriers
            const float4* n4 =
                reinterpret_cast<const float4*>(x + base + (size_t)(p + 1) * HW);
            #pragma unroll
            for (int j = 0; j < 8; ++j) nxt[j] = n4[t + j * 512];
        }
        wg_barrier();
        phaseB(lds, r, t);
        wg_barrier();
        phaseC(lds, r, t);

        float* dst = out + base + (size_t)p * HW;
        const int dT = ((t & 63) << 1) + ((t >> 6) << 11);
        #pragma unroll
        for (int j = 0; j < 4; ++j) {
            const int jb = dT + ((j & 1) << 9) + ((j >> 1) << 10);
            const float* lo = reinterpret_cast<const float*>(&r[j]);
            const float* hi = reinterpret_cast<const float*>(&r[j + 4]);
            #pragma unroll
            for (int c = 0; c < 4; ++c) {
                const int d = jb + ((c & 1) << 7) + ((c >> 1) << 8);
                float2 o; o.x = lo[c]; o.y = hi[c];
                *reinterpret_cast<float2*>(dst + d) = o;
            }
        }
        if (p < 3) {
            wg_barrier();
            #pragma unroll
            for (int j = 0; j < 8; ++j) r[j] = nxt[j];
        }
    }
}

__global__ __launch_bounds__(512) void k_wht2d_inv(float* __restrict__ buf,
                                                   const float* __restrict__ x) {
    __shared__ float lds[HW];
    const int t = threadIdx.x;
    const size_t base = (size_t)blockIdx.x * 4 * HW;
    const float s = 1.0f / 16384.0f;
    const int dT = ((t & 63) << 1) + ((t >> 6) << 11);

    float4 r[8], nxt[8];
    {
        const float4* s4 = reinterpret_cast<const float4*>(buf + base);
        #pragma unroll
        for (int j = 0; j < 8; ++j) r[j] = s4[t + j * 512];
    }

    #pragma unroll
    for (int p = 0; p < 4; ++p) {
        phaseA(lds, r, t);

        // residual x for plane p (used in epilogue; crosses 2 barriers)
        float2 xres[16];
        {
            const float* xr = x + base + (size_t)p * HW;
            #pragma unroll
            for (int j = 0; j < 4; ++j) {
                const int jb = dT + ((j & 1) << 9) + ((j >> 1) << 10);
                #pragma unroll
                for (int c = 0; c < 4; ++c)
                    xres[j * 4 + c] = *reinterpret_cast<const float2*>(
                        xr + jb + ((c & 1) << 7) + ((c >> 1) << 8));
            }
        }
        if (p < 3) {  // prefetch next plane of buf
            const float4* n4 =
                reinterpret_cast<const float4*>(buf + base + (size_t)(p + 1) * HW);
            #pragma unroll
            for (int j = 0; j < 8; ++j) nxt[j] = n4[t + j * 512];
        }
        wg_barrier();
        phaseB(lds, r, t);
        wg_barrier();
        phaseC(lds, r, t);

        float* dst = buf + base + (size_t)p * HW;
        #pragma unroll
        for (int j = 0; j < 4; ++j) {
            const int jb = dT + ((j & 1) << 9) + ((j >> 1) << 10);
            const float* lo = reinterpret_cast<const float*>(&r[j]);
            const float* hi = reinterpret_cast<const float*>(&r[j + 4]);
            #pragma unroll
            for (int c = 0; c < 4; ++c) {
                const int d = jb + ((c & 1) << 7) + ((c >> 1) << 8);
                float2 xv = xres[j * 4 + c];
                float2 o;
                o.x = lo[c] * s + xv.x;
                o.y = hi[c] * s + xv.y;
                *reinterpret_cast<float2*>(dst + d) = o;
            }
        }
        if (p < 3) {
            wg_barrier();
            #pragma unroll
            for (int j = 0; j < 8; ++j) r[j] = nxt[j];
        }
    }
}

// ---------------------------------------------------------------------------
// Channel mix via bf16 MFMA (unchanged): per b,
// Out = W(64x64) . (v .* f2)(64 x 16384), soft-threshold fused, in-place.
// ---------------------------------------------------------------------------
__global__ __launch_bounds__(256) void k_mix_mfma(float* __restrict__ buf,
                                                  const float* __restrict__ W,
                                                  const float* __restrict__ v,
                                                  const float* __restrict__ T) {
    __shared__ float Xs[64 * 128];  // 32 KiB
    const int t = threadIdx.x;
    const int l = t & 63, w = t >> 6;
    const int b  = blockIdx.x >> 7;
    const int p0 = (blockIdx.x & 127) << 7;
    float* base = buf + (size_t)b * 64 * HW + p0;

    bf16x8 A[4][2];
    {
        const int row = l & 15;
        const int kc  = (l >> 4) * 8;
        #pragma unroll
        for (int mt = 0; mt < 4; ++mt) {
            const float* wr = W + (mt * 16 + row) * 64 + kc;
            #pragma unroll
            for (int ks = 0; ks < 2; ++ks) {
                float4 w0 = *reinterpret_cast<const float4*>(wr + ks * 32);
                float4 w1 = *reinterpret_cast<const float4*>(wr + ks * 32 + 4);
                bf16x8 a;
                a[0] = (__bf16)w0.x; a[1] = (__bf16)w0.y;
                a[2] = (__bf16)w0.z; a[3] = (__bf16)w0.w;
                a[4] = (__bf16)w1.x; a[5] = (__bf16)w1.y;
                a[6] = (__bf16)w1.z; a[7] = (__bf16)w1.w;
                A[mt][ks] = a;
            }
        }
    }

    #pragma unroll
    for (int i = 0; i < 8; ++i) {
        const int d  = i * 1024 + t * 4;
        const int c  = d >> 7;
        const int pq = d & 127;
        float4 xv = *reinterpret_cast<const float4*>(base + (size_t)c * HW + pq);
        float4 vv = *reinterpret_cast<const float4*>(v + p0 + pq);
        float4 r;
        r.x = xv.x * vv.x; r.y = xv.y * vv.y;
        r.z = xv.z * vv.z; r.w = xv.w * vv.w;
        const int gc = (c >> 3) & 3;
        *reinterpret_cast<float4*>(Xs + c * 128 + (pq ^ (gc << 4))) = r;
    }
    __syncthreads();

    f32x4 acc[4][2] = {};
    const int n0 = w * 32;
    const int g  = l >> 4;
    #pragma unroll
    for (int nt = 0; nt < 2; ++nt) {
        const int pl = n0 + nt * 16 + (l & 15);
        #pragma unroll
        for (int ks = 0; ks < 2; ++ks) {
            const float* col = Xs + (ks * 32 + g * 8) * 128 + (pl ^ (g << 4));
            bf16x8 bb;
            #pragma unroll
            for (int j = 0; j < 8; ++j) bb[j] = (__bf16)col[j * 128];
            #pragma unroll
            for (int mt = 0; mt < 4; ++mt)
                acc[mt][nt] = __builtin_amdgcn_mfma_f32_16x16x32_bf16(
                    A[mt][ks], bb, acc[mt][nt], 0, 0, 0);
        }
    }

    #pragma unroll
    for (int nt = 0; nt < 2; ++nt) {
        const int p  = p0 + n0 + nt * 16 + (l & 15);
        const float Tp = fmaxf(T[p], 0.0f);
        #pragma unroll
        for (int mt = 0; mt < 4; ++mt) {
            #pragma unroll
            for (int r = 0; r < 4; ++r) {
                const int o = mt * 16 + g * 4 + r;
                float val = acc[mt][nt][r];
                float mag = fmaxf(fabsf(val) - Tp, 0.0f);
                buf[(size_t)b * 64 * HW + (size_t)o * HW + p] = copysignf(mag, val);
            }
        }
    }
}

extern "C" void kernel_launch(void* const* d_in, const int* in_sizes, int n_in,
                              void* d_out, int out_size, void* d_ws, size_t ws_size,
                              hipStream_t stream) {
    const float* x = (const float*)d_in[0];
    const float* W = (const float*)d_in[1];
    const float* v = (const float*)d_in[2];
    const float* T = (const float*)d_in[3];
    float* out = (float*)d_out;

    // f2 = WHT2D(x) -> d_out   (512 blocks x 4 planes, all co-resident)
    k_wht2d_fwd<<<512, 512, 0, stream>>>(x, out);
    // f6 = soft_threshold(W @ (v .* f2), T) -> d_out (in place)
    k_mix_mfma<<<32 * 128, 256, 0, stream>>>(out, W, v, T);
    // y = WHT2D(f6)/16384 + x -> d_out (in place)
    k_wht2d_inv<<<512, 512, 0, stream>>>(out, x);
}

// Round 8
// 145.111 us; speedup vs baseline: 1.0896x; 1.0896x over previous
//
#include <hip/hip_runtime.h>
#include <math.h>

// Problem constants: B=32, C=64, H=128, W=128
#define HW 16384         // plane elements
#define NPLANE 2048      // B*C planes
#define SLOTB 65536ull   // bytes per plane slot in d_out (fp32 plane)

typedef __fp16 f16x2 __attribute__((ext_vector_type(2)));
typedef __bf16 bf16x8 __attribute__((ext_vector_type(8)));
typedef float  f32x4  __attribute__((ext_vector_type(4)));

__device__ __forceinline__ unsigned pk16(float a, float b) {
    f16x2 h = __builtin_amdgcn_cvt_pkrtz(a, b);
    return __builtin_bit_cast(unsigned, h);
}
__device__ __forceinline__ float2 up16(unsigned u) {
    f16x2 h = __builtin_bit_cast(f16x2, u);
    return make_float2((float)h[0], (float)h[1]);
}
__device__ __forceinline__ float bf2f(unsigned short s) {
    unsigned u = (unsigned)s << 16;
    return __builtin_bit_cast(float, u);
}
__device__ __forceinline__ unsigned short f2bf(float f) {
    __bf16 h = (__bf16)f;
    return __builtin_bit_cast(unsigned short, h);
}

__device__ __forceinline__ void bf_quad(float4& a) {
    float s0 = a.x + a.y, d0 = a.x - a.y;
    float s1 = a.z + a.w, d1 = a.z - a.w;
    a.x = s0 + s1; a.y = d0 + d1; a.z = s0 - s1; a.w = d0 - d1;
}
__device__ __forceinline__ void bf_pair(float4& a, float4& b) {
    float4 s, d;
    s.x = a.x + b.x; s.y = a.y + b.y; s.z = a.z + b.z; s.w = a.w + b.w;
    d.x = a.x - b.x; d.y = a.y - b.y; d.z = a.z - b.z; d.w = a.w - b.w;
    a = s; b = d;
}

// ---------------------------------------------------------------------------
// 14-stage WHT over one 16384 plane. 256 threads x 64 elems.
// Element bits i0..i13. Input r[16] float4: (i0,i1)=comp, i2..i9=t, i10..i13=j.
// LDS: 8192 u32 words (32 KiB), word = fp16 pair over i0; word bits w0..w12 =
// i1..i13. Phys swizzle: p2=w2^w5, p3=w3^w6, p4=w4^w7, else identity ->
// A (b64 store), B (b128 rw), C (b64 read) all bank-uniform.
// Phase A: bits {0,1} quad + {10,11,12,13} regs.
// Phase B: bit {2} (in-b128) + {3,4,5} regs.
// Phase C: bits {6,7,8,9} regs.
// Output c[16]: (i0,i1)=comp, i2..i5 = t&15, i6..i9 = k, i10..i13 = t>>4.
// ---------------------------------------------------------------------------
__device__ __forceinline__ void wht_ABC(float4 (&r)[16], unsigned* lds, int t,
                                        float4 (&c)[16]) {
    const int t0 = t & 1, t1 = (t >> 1) & 1, t2 = (t >> 2) & 1, t3 = (t >> 3) & 1;
    const int t4 = (t >> 4) & 1, t5 = (t >> 5) & 1, t6 = (t >> 6) & 1;
    const int thi = t >> 4;  // bits i10..i13 owner in C; w5..w8 source in A

    // ---- Phase A ----
    #pragma unroll
    for (int j = 0; j < 16; ++j) bf_quad(r[j]);
    #pragma unroll
    for (int m = 1; m <= 8; m <<= 1) {
        #pragma unroll
        for (int j = 0; j < 16; ++j) {
            if (!(j & m)) bf_pair(r[j], r[j | m]);
        }
    }
    const int wA = (t0 << 1) | ((t1 ^ t4) << 2) | ((t2 ^ t5) << 3)
                 | ((t3 ^ t6) << 4) | (thi << 5);
    #pragma unroll
    for (int j = 0; j < 16; ++j) {
        uint2 u;
        u.x = pk16(r[j].x, r[j].y);   // i1=0: (i0=0, i0=1)
        u.y = pk16(r[j].z, r[j].w);   // i1=1
        *reinterpret_cast<uint2*>(lds + wA + (j << 9)) = u;
    }
    __syncthreads();

    // ---- Phase B ----  thread bits: i6..i13 = t0..t7; regs j=(i3,i4,i5)
    float e[8][8];
    const int wB = ((t & 15) << 5) | (thi << 9);
    int wb[8];
    #pragma unroll
    for (int j = 0; j < 8; ++j) {
        wb[j] = wB | ((j ^ (t & 7)) << 2);
        uint4 u = *reinterpret_cast<const uint4*>(lds + wb[j]);
        float2 f0 = up16(u.x), f1 = up16(u.y), f2 = up16(u.z), f3 = up16(u.w);
        e[j][0] = f0.x; e[j][1] = f0.y; e[j][2] = f1.x; e[j][3] = f1.y;
        e[j][4] = f2.x; e[j][5] = f2.y; e[j][6] = f3.x; e[j][7] = f3.y;
    }
    #pragma unroll
    for (int j = 0; j < 8; ++j) {      // bit i2: q vs q+4
        #pragma unroll
        for (int q = 0; q < 4; ++q) {
            float a = e[j][q], b = e[j][q + 4];
            e[j][q] = a + b; e[j][q + 4] = a - b;
        }
    }
    #pragma unroll
    for (int m = 1; m <= 4; m <<= 1) { // bits i3,i4,i5
        #pragma unroll
        for (int j = 0; j < 8; ++j) {
            if (!(j & m)) {
                #pragma unroll
                for (int q = 0; q < 8; ++q) {
                    float a = e[j][q], b = e[j | m][q];
                    e[j][q] = a + b; e[j | m][q] = a - b;
                }
            }
        }
    }
    #pragma unroll
    for (int j = 0; j < 8; ++j) {
        uint4 u;
        u.x = pk16(e[j][0], e[j][1]);
        u.y = pk16(e[j][2], e[j][3]);
        u.z = pk16(e[j][4], e[j][5]);
        u.w = pk16(e[j][6], e[j][7]);
        *reinterpret_cast<uint4*>(lds + wb[j]) = u;
    }
    __syncthreads();

    // ---- Phase C ----  thread bits: i2..i5 = t0..t3, i10..i13 = t4..t7
    const int wC = (t0 << 1) | (thi << 9);
    const int tm = (t >> 1) & 7;
    #pragma unroll
    for (int k = 0; k < 16; ++k) {
        const int w = wC | (((k & 7) ^ tm) << 2) | (k << 5);
        uint2 u = *reinterpret_cast<const uint2*>(lds + w);
        float2 f0 = up16(u.x), f1 = up16(u.y);
        c[k].x = f0.x; c[k].y = f0.y; c[k].z = f1.x; c[k].w = f1.y;
    }
    #pragma unroll
    for (int m = 1; m <= 8; m <<= 1) { // bits i6..i9
        #pragma unroll
        for (int k = 0; k < 16; ++k) {
            if (!(k & m)) bf_pair(c[k], c[k | m]);
        }
    }
}

// fwd: f2v = v .* WHT2D(x), stored bf16 into first 32 KiB of each plane slot.
__global__ __launch_bounds__(256, 4) void k_fwd(const float* __restrict__ x,
                                                void* outbuf,
                                                const float* __restrict__ v) {
    __shared__ unsigned lds[8192];
    const int t = threadIdx.x;
    const int plane = blockIdx.x;
    const float4* s4 = reinterpret_cast<const float4*>(x + (size_t)plane * HW);

    float4 r[16];
    #pragma unroll
    for (int j = 0; j < 16; ++j) r[j] = s4[t + j * 256];

    float4 c[16];
    wht_ABC(r, lds, t, c);

    ushort4* dst = reinterpret_cast<ushort4*>((char*)outbuf + (size_t)plane * SLOTB);
    const int obase = (t & 15) + ((t >> 4) << 8);  // float4-unit offset
    #pragma unroll
    for (int k = 0; k < 16; ++k) {
        const int o4 = obase + (k << 4);
        const float4 vv = *reinterpret_cast<const float4*>(v + (o4 << 2));
        ushort4 u;
        u.x = f2bf(c[k].x * vv.x);
        u.y = f2bf(c[k].y * vv.y);
        u.z = f2bf(c[k].z * vv.z);
        u.w = f2bf(c[k].w * vv.w);
        dst[o4] = u;
    }
}

// inv: y = WHT2D(f6)/16384 + x, reads bf16 f6 from slot head, writes fp32 y
// over the full slot (read-before-write within block -> in-place safe).
__global__ __launch_bounds__(256, 4) void k_inv(void* outbuf,
                                                const float* __restrict__ x) {
    __shared__ unsigned lds[8192];
    const int t = threadIdx.x;
    const int plane = blockIdx.x;
    const float sc = 1.0f / 16384.0f;  // pre-scale: keeps fp16 partials small
    const ushort4* src =
        reinterpret_cast<const ushort4*>((const char*)outbuf + (size_t)plane * SLOTB);

    float4 r[16];
    #pragma unroll
    for (int j = 0; j < 16; ++j) {
        ushort4 u = src[t + j * 256];
        r[j].x = bf2f(u.x) * sc; r[j].y = bf2f(u.y) * sc;
        r[j].z = bf2f(u.z) * sc; r[j].w = bf2f(u.w) * sc;
    }

    float4 c[16];
    wht_ABC(r, lds, t, c);

    float* dst = reinterpret_cast<float*>((char*)outbuf + (size_t)plane * SLOTB);
    const float* xr = x + (size_t)plane * HW;
    const int obase = (t & 15) + ((t >> 4) << 8);
    #pragma unroll
    for (int k = 0; k < 16; ++k) {
        const int o4 = obase + (k << 4);
        float4 xv = *reinterpret_cast<const float4*>(xr + (o4 << 2));
        float4 o;
        o.x = c[k].x + xv.x; o.y = c[k].y + xv.y;
        o.z = c[k].z + xv.z; o.w = c[k].w + xv.w;
        *reinterpret_cast<float4*>(dst + (o4 << 2)) = o;
    }
}

// ---------------------------------------------------------------------------
// Channel mix via bf16 MFMA: per b, Out = W(64x64) . f2v(64 x 16384),
// soft-threshold fused; reads/writes bf16 plane-slot heads in place.
// ---------------------------------------------------------------------------
__global__ __launch_bounds__(256) void k_mix_mfma(void* buf,
                                                  const float* __restrict__ W,
                                                  const float* __restrict__ T) {
    __shared__ float Xs[64 * 128];  // 32 KiB
    const int t = threadIdx.x;
    const int l = t & 63, w = t >> 6;
    const int b  = blockIdx.x >> 7;
    const int p0 = (blockIdx.x & 127) << 7;

    bf16x8 A[4][2];
    {
        const int row = l & 15;
        const int kc  = (l >> 4) * 8;
        #pragma unroll
        for (int mt = 0; mt < 4; ++mt) {
            const float* wr = W + (mt * 16 + row) * 64 + kc;
            #pragma unroll
            for (int ks = 0; ks < 2; ++ks) {
                float4 w0 = *reinterpret_cast<const float4*>(wr + ks * 32);
                float4 w1 = *reinterpret_cast<const float4*>(wr + ks * 32 + 4);
                bf16x8 a;
                a[0] = (__bf16)w0.x; a[1] = (__bf16)w0.y;
                a[2] = (__bf16)w0.z; a[3] = (__bf16)w0.w;
                a[4] = (__bf16)w1.x; a[5] = (__bf16)w1.y;
                a[6] = (__bf16)w1.z; a[7] = (__bf16)w1.w;
                A[mt][ks] = a;
            }
        }
    }

    #pragma unroll
    for (int i = 0; i < 8; ++i) {
        const int d  = i * 1024 + t * 4;
        const int cc = d >> 7;
        const int pq = d & 127;
        const ushort4* src = reinterpret_cast<const ushort4*>(
            (const char*)buf + (size_t)(b * 64 + cc) * SLOTB);
        ushort4 u = src[(p0 + pq) >> 2];
        float4 r;
        r.x = bf2f(u.x); r.y = bf2f(u.y); r.z = bf2f(u.z); r.w = bf2f(u.w);
        const int gc = (cc >> 3) & 3;
        *reinterpret_cast<float4*>(Xs + cc * 128 + (pq ^ (gc << 4))) = r;
    }
    __syncthreads();

    f32x4 acc[4][2] = {};
    const int n0 = w * 32;
    const int g  = l >> 4;
    #pragma unroll
    for (int nt = 0; nt < 2; ++nt) {
        const int pl = n0 + nt * 16 + (l & 15);
        #pragma unroll
        for (int ks = 0; ks < 2; ++ks) {
            const float* col = Xs + (ks * 32 + g * 8) * 128 + (pl ^ (g << 4));
            bf16x8 bb;
            #pragma unroll
            for (int j = 0; j < 8; ++j) bb[j] = (__bf16)col[j * 128];
            #pragma unroll
            for (int mt = 0; mt < 4; ++mt)
                acc[mt][nt] = __builtin_amdgcn_mfma_f32_16x16x32_bf16(
                    A[mt][ks], bb, acc[mt][nt], 0, 0, 0);
        }
    }

    #pragma unroll
    for (int nt = 0; nt < 2; ++nt) {
        const int p  = p0 + n0 + nt * 16 + (l & 15);
        const float Tp = fmaxf(T[p], 0.0f);
        #pragma unroll
        for (int mt = 0; mt < 4; ++mt) {
            unsigned short* orow = reinterpret_cast<unsigned short*>(
                (char*)buf + (size_t)(b * 64 + mt * 16 + g * 4) * SLOTB);
            #pragma unroll
            for (int r = 0; r < 4; ++r) {
                float val = acc[mt][nt][r];
                float mag = fmaxf(fabsf(val) - Tp, 0.0f);
                reinterpret_cast<unsigned short*>(
                    (char*)orow + (size_t)r * SLOTB)[p] = f2bf(copysignf(mag, val));
            }
        }
    }
}

extern "C" void kernel_launch(void* const* d_in, const int* in_sizes, int n_in,
                              void* d_out, int out_size, void* d_ws, size_t ws_size,
                              hipStream_t stream) {
    const float* x = (const float*)d_in[0];
    const float* W = (const float*)d_in[1];
    const float* v = (const float*)d_in[2];
    const float* T = (const float*)d_in[3];

    // f2v = v .* WHT2D(x) -> bf16, slot heads of d_out
    k_fwd<<<NPLANE, 256, 0, stream>>>(x, d_out, v);
    // f6 = soft_threshold(W @ f2v, T) -> bf16, in place
    k_mix_mfma<<<32 * 128, 256, 0, stream>>>(d_out, W, T);
    // y = WHT2D(f6)/16384 + x -> fp32, full slots of d_out
    k_inv<<<NPLANE, 256, 0, stream>>>(d_out, x);
}